// Round 16
// baseline (197.222 us; speedup 1.0000x reference)
//
#include <hip/hip_runtime.h>

// GIN GNN on MI355X. R16 = R15 with: gather rounds widened 8 -> 16 (typical
// chain = ONE memory round-trip; add order unchanged -> bit-identical absmax
// 0.375); csort 8 edges/thread. Everything else identical to R15.

#define FEAT 128
#define CAP 128
#define SPILLCAP 4096

typedef unsigned short u16;
typedef unsigned int u32;
typedef __attribute__((ext_vector_type(8))) short bf16x8;
typedef __attribute__((ext_vector_type(4))) float f32x4;

__device__ __forceinline__ u32 f2bf(float f) {
    u32 u = __float_as_uint(f);
    return (u + 0x7FFFu + ((u >> 16) & 1u)) >> 16;   // RNE
}
__device__ __forceinline__ float bf2f(u32 u) { return __uint_as_float(u << 16); }
__device__ __forceinline__ float bflo(u32 u) { return __uint_as_float(u << 16); }
__device__ __forceinline__ float bfhi(u32 u) { return __uint_as_float(u & 0xFFFF0000u); }

__device__ __forceinline__ void add8(uint4 v, float* a) {
    a[0] += bflo(v.x); a[1] += bfhi(v.x);
    a[2] += bflo(v.y); a[3] += bfhi(v.y);
    a[4] += bflo(v.z); a[5] += bfhi(v.z);
    a[6] += bflo(v.w); a[7] += bfhi(v.w);
}

// ------ prep: x fp32 -> bf16; zero cnt + spillCnt ------
__global__ __launch_bounds__(256) void cvt_x_kernel(
    const float* __restrict__ x, u16* __restrict__ xb, int total4,
    int* __restrict__ cnt, int n, int* __restrict__ spillCnt)
{
    int i = blockIdx.x * 256 + threadIdx.x;
    if (i < n) cnt[i] = 0;
    if (i == 0) *spillCnt = 0;
    if (i >= total4) return;
    float4 v = reinterpret_cast<const float4*>(x)[i];
    u32 lo = f2bf(v.x) | (f2bf(v.y) << 16);
    u32 hi = f2bf(v.z) | (f2bf(v.w) << 16);
    reinterpret_cast<uint2*>(xb)[i] = make_uint2(lo, hi);
}

// ------------- prep: W fp32 [k][n] -> Wt bf16 hi/lo [n][k], 6 mats; y==6: bounds ----
struct WSet { const float* w[6]; };
__global__ __launch_bounds__(256) void cvt_wt_bounds_kernel(
    WSet ws, u16* __restrict__ outHi, u16* __restrict__ outLo,
    const int* __restrict__ batch, int* __restrict__ bnd, int n, int G)
{
    if (blockIdx.y == 6) {
        int g = blockIdx.x * 256 + threadIdx.x;
        if (g > G) return;
        int lo = 0, hi = n;
        while (lo < hi) {
            int mid = (lo + hi) >> 1;
            if (batch[mid] < g) lo = mid + 1; else hi = mid;
        }
        bnd[g] = lo;
        return;
    }
    int mat = blockIdx.y;
    const float* W = ws.w[mat];
    int i = blockIdx.x * 256 + threadIdx.x;   // 0..16383
    int nn = i >> 7, k = i & 127;
    float f = W[(size_t)k * FEAT + nn];
    u32 hi = f2bf(f);
    u32 lo = f2bf(f - bf2f(hi));
    size_t o = (size_t)mat * FEAT * FEAT + (size_t)nn * FEAT + k;
    outHi[o] = (u16)hi;
    outLo[o] = (u16)lo;
}

// ---------------- bucket scatter: esrc[d*CAP + slot] = src; 8 edges/thread ------------
__global__ __launch_bounds__(256) void csort_bucket_kernel(
    const int* __restrict__ src, const int* __restrict__ dst,
    int* __restrict__ cnt, u16* __restrict__ esrc,
    int* __restrict__ spillCnt, int2* __restrict__ spill, int nE)
{
    int e8 = (blockIdx.x * 256 + threadIdx.x) * 8;
    if (e8 + 7 < nE) {
#pragma unroll
        for (int h = 0; h < 2; ++h) {
            int4 d = *reinterpret_cast<const int4*>(&dst[e8 + h * 4]);
            int4 sv = *reinterpret_cast<const int4*>(&src[e8 + h * 4]);
            int p0 = atomicAdd(&cnt[d.x], 1);
            int p1 = atomicAdd(&cnt[d.y], 1);
            int p2 = atomicAdd(&cnt[d.z], 1);
            int p3 = atomicAdd(&cnt[d.w], 1);
            if (p0 < CAP) esrc[(size_t)d.x * CAP + p0] = (u16)sv.x;
            else { int q = atomicAdd(spillCnt, 1); if (q < SPILLCAP) spill[q] = make_int2(d.x, sv.x); }
            if (p1 < CAP) esrc[(size_t)d.y * CAP + p1] = (u16)sv.y;
            else { int q = atomicAdd(spillCnt, 1); if (q < SPILLCAP) spill[q] = make_int2(d.y, sv.y); }
            if (p2 < CAP) esrc[(size_t)d.z * CAP + p2] = (u16)sv.z;
            else { int q = atomicAdd(spillCnt, 1); if (q < SPILLCAP) spill[q] = make_int2(d.z, sv.z); }
            if (p3 < CAP) esrc[(size_t)d.w * CAP + p3] = (u16)sv.w;
            else { int q = atomicAdd(spillCnt, 1); if (q < SPILLCAP) spill[q] = make_int2(d.w, sv.w); }
        }
    } else {
        for (int e = e8; e < nE; ++e) {
            int d = dst[e], s = src[e];
            int p = atomicAdd(&cnt[d], 1);
            if (p < CAP) esrc[(size_t)d * CAP + p] = (u16)s;
            else { int q = atomicAdd(spillCnt, 1); if (q < SPILLCAP) spill[q] = make_int2(d, s); }
        }
    }
}

// -------- fused GIN layer: out(bf16) = relu(relu((gather hin)@W1+b1)@W2+b2) ------
// 512 threads = 8 waves. Phase A0: stage esrc (4KB) to LDS. Phase A: 16 nodes x
// 2 groups x 16 lanes, ONE masked 16-wide round typical. Phase B: 8 waves x 1 tile.
__global__ __launch_bounds__(512) void gin_layer_kernel(
    const u16* __restrict__ hin, const int* __restrict__ cnt,
    const u16* __restrict__ esrc,
    const int* __restrict__ spillCnt, const int2* __restrict__ spill,
    const u16* __restrict__ W1h, const u16* __restrict__ W1l,
    const float* __restrict__ B1,
    const u16* __restrict__ W2h, const u16* __restrict__ W2l,
    const float* __restrict__ B2,
    u16* __restrict__ out, int n)
{
    __shared__ float z_lds[2][16][132];  // 16.9 KB (+4 pad per row)
    __shared__ u16 e_lds[16 * CAP];      // 4 KB staged edge indices
    __shared__ u16 thi_lds[16 * FEAT];   // 4 KB
    __shared__ u16 tlo_lds[16 * FEAT];   // 4 KB

    int tid = threadIdx.x;
    int rowBase = blockIdx.x * 16;

    // ---- phase A0: stage esrc for the block's 16 nodes (coalesced 4KB) ----
    reinterpret_cast<uint2*>(e_lds)[tid] =
        reinterpret_cast<const uint2*>(esrc)[(size_t)rowBase * (CAP / 4) + tid];

    __syncthreads();

    // ---- phase A: gather z rows; 2 groups of 16 lanes per node; 16-wide rounds ----
    {
        int nr = tid >> 5;          // 0..15 node slot
        int grp = (tid >> 4) & 1;   // edge-group
        int lane = tid & 15;        // 16 lanes x 16B = 256B row
        int node = rowBase + nr;
        const uint4* h4 = reinterpret_cast<const uint4*>(hin);
        float a[8] = {0.f, 0.f, 0.f, 0.f, 0.f, 0.f, 0.f, 0.f};
        if (grp == 0) {   // self term (eps=0)
            uint4 u = h4[(size_t)node * 16 + lane];
            add8(u, a);
        }
        int len = cnt[node];
        if (len > CAP) len = CAP;
        int half = (len + 1) >> 1;
        int gbeg = grp * half;
        int gend = grp ? len : half;
        const u16* eb = &e_lds[nr * CAP];
        for (int j = gbeg; j < gend; j += 16) {   // masked 16-wide rounds
            uint4 v[16];
#pragma unroll
            for (int q = 0; q < 16; ++q) {
                int jj = j + q;
                int jc = jj < gend ? jj : (gend - 1);
                v[q] = h4[(size_t)eb[jc] * 16 + lane];
                u32 m = (jj < gend) ? 0xFFFFFFFFu : 0u;
                v[q].x &= m; v[q].y &= m; v[q].z &= m; v[q].w &= m;
            }
#pragma unroll
            for (int q = 0; q < 16; ++q) add8(v[q], a);
        }
        if (grp == 0) {   // spill pass (normally 0 entries)
            int sc = *spillCnt;
            if (sc > SPILLCAP) sc = SPILLCAP;
            for (int i = 0; i < sc; ++i) {
                int2 e = spill[i];
                if (e.x == node) {
                    uint4 v = h4[(size_t)e.y * 16 + lane];
                    add8(v, a);
                }
            }
        }
        *reinterpret_cast<float4*>(&z_lds[grp][nr][lane * 8]) =
            make_float4(a[0], a[1], a[2], a[3]);
        *reinterpret_cast<float4*>(&z_lds[grp][nr][lane * 8 + 4]) =
            make_float4(a[4], a[5], a[6], a[7]);
    }

    __syncthreads();

    int w = tid >> 6;          // 0..7 wave id = col tile
    int l = tid & 63;
    int l16 = l & 15;
    int lq = l >> 4;           // 0..3

    // ---- A fragments: z = z0 + z1 from LDS partials; split hi/lo ----
    bf16x8 ah[4], al[4];
#pragma unroll
    for (int q = 0; q < 4; ++q) {
        const float* zr0 = &z_lds[0][l16][q * 32 + lq * 8];
        const float* zr1 = &z_lds[1][l16][q * 32 + lq * 8];
        float4 f0 = *reinterpret_cast<const float4*>(zr0);
        float4 f1 = *reinterpret_cast<const float4*>(zr0 + 4);
        float4 g0 = *reinterpret_cast<const float4*>(zr1);
        float4 g1 = *reinterpret_cast<const float4*>(zr1 + 4);
        float fv[8] = {f0.x + g0.x, f0.y + g0.y, f0.z + g0.z, f0.w + g0.w,
                       f1.x + g1.x, f1.y + g1.y, f1.z + g1.z, f1.w + g1.w};
        bf16x8 hv, lv;
#pragma unroll
        for (int i = 0; i < 8; ++i) {
            u32 hb = f2bf(fv[i]);
            u32 lb = f2bf(fv[i] - bf2f(hb));
            hv[i] = (short)hb; lv[i] = (short)lb;
        }
        ah[q] = hv; al[q] = lv;
    }

    f32x4 acc = (f32x4){0.f, 0.f, 0.f, 0.f};

    // ---- GEMM1: (Ah+Al) @ (W1h+W1l), dropping Al*W1l; tile ct = w ----
    {
        const bf16x8* WrowH = reinterpret_cast<const bf16x8*>(W1h + (size_t)(w * 16 + l16) * FEAT);
        const bf16x8* WrowL = reinterpret_cast<const bf16x8*>(W1l + (size_t)(w * 16 + l16) * FEAT);
#pragma unroll
        for (int q = 0; q < 4; ++q) {
            bf16x8 wh = WrowH[q * 4 + lq];
            bf16x8 wl = WrowL[q * 4 + lq];
            acc = __builtin_amdgcn_mfma_f32_16x16x32_bf16(ah[q], wh, acc, 0, 0, 0);
            acc = __builtin_amdgcn_mfma_f32_16x16x32_bf16(al[q], wh, acc, 0, 0, 0);
            acc = __builtin_amdgcn_mfma_f32_16x16x32_bf16(ah[q], wl, acc, 0, 0, 0);
        }
    }

    // ---- epilogue1: bias+relu -> split t in LDS (XOR-swizzled 16B chunks) ----
    {
        int col = w * 16 + l16;
        float bias = B1[col];
        int base16 = (w * 32) + ((l16 & 8) << 1);
        int fine = (l16 & 7) << 1;
#pragma unroll
        for (int r = 0; r < 4; ++r) {
            int rt = lq * 4 + r;
            float v = fmaxf(acc[r] + bias, 0.0f);
            u32 hi = f2bf(v);
            u32 lo = f2bf(v - bf2f(hi));
            int idx = (rt * 256 + ((base16 ^ (rt << 4)) | fine)) >> 1;
            thi_lds[idx] = (u16)hi;
            tlo_lds[idx] = (u16)lo;
        }
    }

    __syncthreads();

    // ---- A2 fragments from LDS (row l16, swizzle-matched) ----
    const bf16x8* thb = reinterpret_cast<const bf16x8*>(thi_lds);
    const bf16x8* tlb = reinterpret_cast<const bf16x8*>(tlo_lds);
    bf16x8 a2h[4], a2l[4];
#pragma unroll
    for (int q = 0; q < 4; ++q) {
        int idx = l16 * 16 + ((q * 4 + lq) ^ l16);
        a2h[q] = thb[idx];
        a2l[q] = tlb[idx];
    }

    acc = (f32x4){0.f, 0.f, 0.f, 0.f};

    // ---- GEMM2: (th+tl) @ (W2h+W2l), dropping tl*W2l; tile ct = w ----
    {
        const bf16x8* WrowH = reinterpret_cast<const bf16x8*>(W2h + (size_t)(w * 16 + l16) * FEAT);
        const bf16x8* WrowL = reinterpret_cast<const bf16x8*>(W2l + (size_t)(w * 16 + l16) * FEAT);
#pragma unroll
        for (int q = 0; q < 4; ++q) {
            bf16x8 wh = WrowH[q * 4 + lq];
            bf16x8 wl = WrowL[q * 4 + lq];
            acc = __builtin_amdgcn_mfma_f32_16x16x32_bf16(a2h[q], wh, acc, 0, 0, 0);
            acc = __builtin_amdgcn_mfma_f32_16x16x32_bf16(a2l[q], wh, acc, 0, 0, 0);
            acc = __builtin_amdgcn_mfma_f32_16x16x32_bf16(a2h[q], wl, acc, 0, 0, 0);
        }
    }

    // ---- epilogue2: bias+relu -> out (bf16) ----
    {
        int col = w * 16 + l16;
        float bias = B2[col];
#pragma unroll
        for (int r = 0; r < 4; ++r) {
            int m = rowBase + lq * 4 + r;
            float v = fmaxf(acc[r] + bias, 0.0f);
            out[(size_t)m * FEAT + col] = (u16)f2bf(v);
        }
    }
}

// ---------------- pool + head fused: one block per graph ----------------
__global__ __launch_bounds__(128) void pool_head_kernel(
    const u16* __restrict__ h, const int* __restrict__ bnd,
    const float* __restrict__ w1, const float* __restrict__ b1,
    const float* __restrict__ w2, const float* __restrict__ b2,
    float* __restrict__ out)
{
    int g = blockIdx.x;
    int f = threadIdx.x;   // 0..127
    __shared__ float p[FEAT];
    int beg = bnd[g], end = bnd[g + 1];
    float s = 0.0f;
    for (int i = beg; i < end; ++i)
        s += __uint_as_float((u32)h[(size_t)i * FEAT + f] << 16);
    float inv = (end > beg) ? 1.0f / (float)(end - beg) : 1.0f;
    p[f] = s * inv;
    __syncthreads();
    if (f < 64) {
        int j = f;
        float acc = b1[j];
#pragma unroll 8
        for (int k = 0; k < FEAT; ++k) acc = fmaf(p[k], w1[k * 64 + j], acc);
        float hid = fmaxf(acc, 0.0f);
        float prod = hid * w2[j];
#pragma unroll
        for (int off = 32; off > 0; off >>= 1) prod += __shfl_down(prod, off);
        if (j == 0) out[g] = prod + b2[0];
    }
}

extern "C" void kernel_launch(void* const* d_in, const int* in_sizes, int n_in,
                              void* d_out, int out_size, void* d_ws, size_t ws_size,
                              hipStream_t stream) {
    const float* x     = (const float*)d_in[0];
    const int*   ei    = (const int*)d_in[1];
    const int*   batch = (const int*)d_in[2];
    const float* b1[3] = {(const float*)d_in[4], (const float*)d_in[8], (const float*)d_in[12]};
    const float* b2[3] = {(const float*)d_in[6], (const float*)d_in[10], (const float*)d_in[14]};
    const float* hw1 = (const float*)d_in[15];
    const float* hb1 = (const float*)d_in[16];
    const float* hw2 = (const float*)d_in[17];
    const float* hb2 = (const float*)d_in[18];

    int N = in_sizes[0] / FEAT;     // 20000
    int E = in_sizes[1] / 2;        // 640000
    int G = out_size;               // 256

    // workspace layout (16B-aligned chunks)
    u16* wtsH = (u16*)d_ws;                          // 6 * 128*128 bf16
    u16* wtsL = wtsH + (size_t)6 * FEAT * FEAT;      // 6 * 128*128 bf16
    u16* xb  = wtsL + (size_t)6 * FEAT * FEAT;       // N*128 bf16
    u16* hA  = xb + (size_t)N * FEAT;                // N*128 bf16
    u16* hB  = hA + (size_t)N * FEAT;                // N*128 bf16
    u16* esrc = hB + (size_t)N * FEAT;               // N*CAP u16
    int* bnd      = (int*)(esrc + (size_t)N * CAP);  // G+1
    int* cnt      = bnd + (G + 1);                   // N
    int* spillCnt = cnt + N;                         // 1 (+pad)
    int2* spill   = (int2*)(spillCnt + 4);           // SPILLCAP

    const int* src = ei;
    const int* dstv = ei + E;

    int e8Blocks = (E / 8 + 255) / 256;   // 313

    // ---- prep: cvt x (zeros cnt+spillCnt), cvt weights + graph bounds ----
    cvt_x_kernel<<<(N * FEAT / 4 + 255) / 256, 256, 0, stream>>>(
        x, xb, N * FEAT / 4, cnt, N, spillCnt);
    WSet ws;
    ws.w[0] = (const float*)d_in[3];  ws.w[1] = (const float*)d_in[5];
    ws.w[2] = (const float*)d_in[7];  ws.w[3] = (const float*)d_in[9];
    ws.w[4] = (const float*)d_in[11]; ws.w[5] = (const float*)d_in[13];
    cvt_wt_bounds_kernel<<<dim3(64, 7), 256, 0, stream>>>(ws, wtsH, wtsL, batch, bnd, N, G);

    // ---- bucket scatter (replaces hist+scan+csort) ----
    csort_bucket_kernel<<<e8Blocks, 256, 0, stream>>>(
        src, dstv, cnt, esrc, spillCnt, spill, E);

    // ---- 3 fused GIN layers, ping-pong buffers (NO in-place aliasing) ----
    int layerBlocks = (N + 15) / 16;   // 1250
    const u16* lin[3] = {xb, hA, hB};
    u16*       lout[3] = {hA, hB, hA};
    for (int l = 0; l < 3; ++l) {
        gin_layer_kernel<<<layerBlocks, 512, 0, stream>>>(
            lin[l], cnt, esrc, spillCnt, spill,
            wtsH + (size_t)(2 * l) * FEAT * FEAT, wtsL + (size_t)(2 * l) * FEAT * FEAT, b1[l],
            wtsH + (size_t)(2 * l + 1) * FEAT * FEAT, wtsL + (size_t)(2 * l + 1) * FEAT * FEAT, b2[l],
            lout[l], N);
    }

    // ---- pool + head (fused) ----
    pool_head_kernel<<<G, 128, 0, stream>>>(hA, bnd, hw1, hb1, hw2, hb2, (float*)d_out);
}

// Round 17
// 173.870 us; speedup vs baseline: 1.1343x; 1.1343x over previous
//
#include <hip/hip_runtime.h>

// GIN GNN on MI355X. R17 = exact revert to R15 (172us, absmax 0.375).
// R16's 8-edge csort halved TLP on an atomic-latency-bound kernel (-25us);
// 16-wide gather was neutral (gather already at 1-round-trip floor).

#define FEAT 128
#define CAP 128
#define SPILLCAP 4096

typedef unsigned short u16;
typedef unsigned int u32;
typedef __attribute__((ext_vector_type(8))) short bf16x8;
typedef __attribute__((ext_vector_type(4))) float f32x4;

__device__ __forceinline__ u32 f2bf(float f) {
    u32 u = __float_as_uint(f);
    return (u + 0x7FFFu + ((u >> 16) & 1u)) >> 16;   // RNE
}
__device__ __forceinline__ float bf2f(u32 u) { return __uint_as_float(u << 16); }
__device__ __forceinline__ float bflo(u32 u) { return __uint_as_float(u << 16); }
__device__ __forceinline__ float bfhi(u32 u) { return __uint_as_float(u & 0xFFFF0000u); }

__device__ __forceinline__ void add8(uint4 v, float* a) {
    a[0] += bflo(v.x); a[1] += bfhi(v.x);
    a[2] += bflo(v.y); a[3] += bfhi(v.y);
    a[4] += bflo(v.z); a[5] += bfhi(v.z);
    a[6] += bflo(v.w); a[7] += bfhi(v.w);
}

// ------ prep: x fp32 -> bf16; zero cnt + spillCnt ------
__global__ __launch_bounds__(256) void cvt_x_kernel(
    const float* __restrict__ x, u16* __restrict__ xb, int total4,
    int* __restrict__ cnt, int n, int* __restrict__ spillCnt)
{
    int i = blockIdx.x * 256 + threadIdx.x;
    if (i < n) cnt[i] = 0;
    if (i == 0) *spillCnt = 0;
    if (i >= total4) return;
    float4 v = reinterpret_cast<const float4*>(x)[i];
    u32 lo = f2bf(v.x) | (f2bf(v.y) << 16);
    u32 hi = f2bf(v.z) | (f2bf(v.w) << 16);
    reinterpret_cast<uint2*>(xb)[i] = make_uint2(lo, hi);
}

// ------------- prep: W fp32 [k][n] -> Wt bf16 hi/lo [n][k], 6 mats; y==6: bounds ----
struct WSet { const float* w[6]; };
__global__ __launch_bounds__(256) void cvt_wt_bounds_kernel(
    WSet ws, u16* __restrict__ outHi, u16* __restrict__ outLo,
    const int* __restrict__ batch, int* __restrict__ bnd, int n, int G)
{
    if (blockIdx.y == 6) {
        int g = blockIdx.x * 256 + threadIdx.x;
        if (g > G) return;
        int lo = 0, hi = n;
        while (lo < hi) {
            int mid = (lo + hi) >> 1;
            if (batch[mid] < g) lo = mid + 1; else hi = mid;
        }
        bnd[g] = lo;
        return;
    }
    int mat = blockIdx.y;
    const float* W = ws.w[mat];
    int i = blockIdx.x * 256 + threadIdx.x;   // 0..16383
    int nn = i >> 7, k = i & 127;
    float f = W[(size_t)k * FEAT + nn];
    u32 hi = f2bf(f);
    u32 lo = f2bf(f - bf2f(hi));
    size_t o = (size_t)mat * FEAT * FEAT + (size_t)nn * FEAT + k;
    outHi[o] = (u16)hi;
    outLo[o] = (u16)lo;
}

// ---------------- bucket scatter: esrc[d*CAP + slot] = src; 4 edges/thread ------------
__global__ __launch_bounds__(256) void csort_bucket_kernel(
    const int* __restrict__ src, const int* __restrict__ dst,
    int* __restrict__ cnt, u16* __restrict__ esrc,
    int* __restrict__ spillCnt, int2* __restrict__ spill, int nE)
{
    int e4 = (blockIdx.x * 256 + threadIdx.x) * 4;
    if (e4 + 3 < nE) {
        int4 d = *reinterpret_cast<const int4*>(&dst[e4]);
        int4 sv = *reinterpret_cast<const int4*>(&src[e4]);
        int p0 = atomicAdd(&cnt[d.x], 1);
        int p1 = atomicAdd(&cnt[d.y], 1);
        int p2 = atomicAdd(&cnt[d.z], 1);
        int p3 = atomicAdd(&cnt[d.w], 1);
        if (p0 < CAP) esrc[(size_t)d.x * CAP + p0] = (u16)sv.x;
        else { int q = atomicAdd(spillCnt, 1); if (q < SPILLCAP) spill[q] = make_int2(d.x, sv.x); }
        if (p1 < CAP) esrc[(size_t)d.y * CAP + p1] = (u16)sv.y;
        else { int q = atomicAdd(spillCnt, 1); if (q < SPILLCAP) spill[q] = make_int2(d.y, sv.y); }
        if (p2 < CAP) esrc[(size_t)d.z * CAP + p2] = (u16)sv.z;
        else { int q = atomicAdd(spillCnt, 1); if (q < SPILLCAP) spill[q] = make_int2(d.z, sv.z); }
        if (p3 < CAP) esrc[(size_t)d.w * CAP + p3] = (u16)sv.w;
        else { int q = atomicAdd(spillCnt, 1); if (q < SPILLCAP) spill[q] = make_int2(d.w, sv.w); }
    } else {
        for (int e = e4; e < nE; ++e) {
            int d = dst[e], s = src[e];
            int p = atomicAdd(&cnt[d], 1);
            if (p < CAP) esrc[(size_t)d * CAP + p] = (u16)s;
            else { int q = atomicAdd(spillCnt, 1); if (q < SPILLCAP) spill[q] = make_int2(d, s); }
        }
    }
}

// -------- fused GIN layer: out(bf16) = relu(relu((gather hin)@W1+b1)@W2+b2) ------
// 512 threads = 8 waves. Phase A0: stage this block's esrc (16 nodes x CAP u16
// = 4KB) into LDS, one coalesced uint2/thread. Phase A: 16 nodes x 2 groups x
// 16 lanes, masked 8-wide rounds, indices from LDS. Phase B: 8 waves x 1 tile.
__global__ __launch_bounds__(512) void gin_layer_kernel(
    const u16* __restrict__ hin, const int* __restrict__ cnt,
    const u16* __restrict__ esrc,
    const int* __restrict__ spillCnt, const int2* __restrict__ spill,
    const u16* __restrict__ W1h, const u16* __restrict__ W1l,
    const float* __restrict__ B1,
    const u16* __restrict__ W2h, const u16* __restrict__ W2l,
    const float* __restrict__ B2,
    u16* __restrict__ out, int n)
{
    __shared__ float z_lds[2][16][132];  // 16.9 KB (+4 pad per row)
    __shared__ u16 e_lds[16 * CAP];      // 4 KB staged edge indices
    __shared__ u16 thi_lds[16 * FEAT];   // 4 KB
    __shared__ u16 tlo_lds[16 * FEAT];   // 4 KB

    int tid = threadIdx.x;
    int rowBase = blockIdx.x * 16;

    // ---- phase A0: stage esrc for the block's 16 nodes (coalesced 4KB) ----
    reinterpret_cast<uint2*>(e_lds)[tid] =
        reinterpret_cast<const uint2*>(esrc)[(size_t)rowBase * (CAP / 4) + tid];

    __syncthreads();

    // ---- phase A: gather z rows; 2 groups of 16 lanes per node ----
    {
        int nr = tid >> 5;          // 0..15 node slot
        int grp = (tid >> 4) & 1;   // edge-group
        int lane = tid & 15;        // 16 lanes x 16B = 256B row
        int node = rowBase + nr;
        const uint4* h4 = reinterpret_cast<const uint4*>(hin);
        float a[8] = {0.f, 0.f, 0.f, 0.f, 0.f, 0.f, 0.f, 0.f};
        if (grp == 0) {   // self term (eps=0)
            uint4 u = h4[(size_t)node * 16 + lane];
            add8(u, a);
        }
        int len = cnt[node];
        if (len > CAP) len = CAP;
        int half = (len + 1) >> 1;
        int gbeg = grp * half;
        int gend = grp ? len : half;
        const u16* eb = &e_lds[nr * CAP];
        for (int j = gbeg; j < gend; j += 8) {   // masked 8-wide rounds
            uint4 v[8];
#pragma unroll
            for (int q = 0; q < 8; ++q) {
                int jj = j + q;
                int jc = jj < gend ? jj : (gend - 1);
                v[q] = h4[(size_t)eb[jc] * 16 + lane];
                u32 m = (jj < gend) ? 0xFFFFFFFFu : 0u;
                v[q].x &= m; v[q].y &= m; v[q].z &= m; v[q].w &= m;
            }
#pragma unroll
            for (int q = 0; q < 8; ++q) add8(v[q], a);
        }
        if (grp == 0) {   // spill pass (normally 0 entries)
            int sc = *spillCnt;
            if (sc > SPILLCAP) sc = SPILLCAP;
            for (int i = 0; i < sc; ++i) {
                int2 e = spill[i];
                if (e.x == node) {
                    uint4 v = h4[(size_t)e.y * 16 + lane];
                    add8(v, a);
                }
            }
        }
        *reinterpret_cast<float4*>(&z_lds[grp][nr][lane * 8]) =
            make_float4(a[0], a[1], a[2], a[3]);
        *reinterpret_cast<float4*>(&z_lds[grp][nr][lane * 8 + 4]) =
            make_float4(a[4], a[5], a[6], a[7]);
    }

    __syncthreads();

    int w = tid >> 6;          // 0..7 wave id = col tile
    int l = tid & 63;
    int l16 = l & 15;
    int lq = l >> 4;           // 0..3

    // ---- A fragments: z = z0 + z1 from LDS partials; split hi/lo ----
    bf16x8 ah[4], al[4];
#pragma unroll
    for (int q = 0; q < 4; ++q) {
        const float* zr0 = &z_lds[0][l16][q * 32 + lq * 8];
        const float* zr1 = &z_lds[1][l16][q * 32 + lq * 8];
        float4 f0 = *reinterpret_cast<const float4*>(zr0);
        float4 f1 = *reinterpret_cast<const float4*>(zr0 + 4);
        float4 g0 = *reinterpret_cast<const float4*>(zr1);
        float4 g1 = *reinterpret_cast<const float4*>(zr1 + 4);
        float fv[8] = {f0.x + g0.x, f0.y + g0.y, f0.z + g0.z, f0.w + g0.w,
                       f1.x + g1.x, f1.y + g1.y, f1.z + g1.z, f1.w + g1.w};
        bf16x8 hv, lv;
#pragma unroll
        for (int i = 0; i < 8; ++i) {
            u32 hb = f2bf(fv[i]);
            u32 lb = f2bf(fv[i] - bf2f(hb));
            hv[i] = (short)hb; lv[i] = (short)lb;
        }
        ah[q] = hv; al[q] = lv;
    }

    f32x4 acc = (f32x4){0.f, 0.f, 0.f, 0.f};

    // ---- GEMM1: (Ah+Al) @ (W1h+W1l), dropping Al*W1l; tile ct = w ----
    {
        const bf16x8* WrowH = reinterpret_cast<const bf16x8*>(W1h + (size_t)(w * 16 + l16) * FEAT);
        const bf16x8* WrowL = reinterpret_cast<const bf16x8*>(W1l + (size_t)(w * 16 + l16) * FEAT);
#pragma unroll
        for (int q = 0; q < 4; ++q) {
            bf16x8 wh = WrowH[q * 4 + lq];
            bf16x8 wl = WrowL[q * 4 + lq];
            acc = __builtin_amdgcn_mfma_f32_16x16x32_bf16(ah[q], wh, acc, 0, 0, 0);
            acc = __builtin_amdgcn_mfma_f32_16x16x32_bf16(al[q], wh, acc, 0, 0, 0);
            acc = __builtin_amdgcn_mfma_f32_16x16x32_bf16(ah[q], wl, acc, 0, 0, 0);
        }
    }

    // ---- epilogue1: bias+relu -> split t in LDS (XOR-swizzled 16B chunks) ----
    {
        int col = w * 16 + l16;
        float bias = B1[col];
        int base16 = (w * 32) + ((l16 & 8) << 1);
        int fine = (l16 & 7) << 1;
#pragma unroll
        for (int r = 0; r < 4; ++r) {
            int rt = lq * 4 + r;
            float v = fmaxf(acc[r] + bias, 0.0f);
            u32 hi = f2bf(v);
            u32 lo = f2bf(v - bf2f(hi));
            int idx = (rt * 256 + ((base16 ^ (rt << 4)) | fine)) >> 1;
            thi_lds[idx] = (u16)hi;
            tlo_lds[idx] = (u16)lo;
        }
    }

    __syncthreads();

    // ---- A2 fragments from LDS (row l16, swizzle-matched) ----
    const bf16x8* thb = reinterpret_cast<const bf16x8*>(thi_lds);
    const bf16x8* tlb = reinterpret_cast<const bf16x8*>(tlo_lds);
    bf16x8 a2h[4], a2l[4];
#pragma unroll
    for (int q = 0; q < 4; ++q) {
        int idx = l16 * 16 + ((q * 4 + lq) ^ l16);
        a2h[q] = thb[idx];
        a2l[q] = tlb[idx];
    }

    acc = (f32x4){0.f, 0.f, 0.f, 0.f};

    // ---- GEMM2: (th+tl) @ (W2h+W2l), dropping tl*W2l; tile ct = w ----
    {
        const bf16x8* WrowH = reinterpret_cast<const bf16x8*>(W2h + (size_t)(w * 16 + l16) * FEAT);
        const bf16x8* WrowL = reinterpret_cast<const bf16x8*>(W2l + (size_t)(w * 16 + l16) * FEAT);
#pragma unroll
        for (int q = 0; q < 4; ++q) {
            bf16x8 wh = WrowH[q * 4 + lq];
            bf16x8 wl = WrowL[q * 4 + lq];
            acc = __builtin_amdgcn_mfma_f32_16x16x32_bf16(a2h[q], wh, acc, 0, 0, 0);
            acc = __builtin_amdgcn_mfma_f32_16x16x32_bf16(a2l[q], wh, acc, 0, 0, 0);
            acc = __builtin_amdgcn_mfma_f32_16x16x32_bf16(a2h[q], wl, acc, 0, 0, 0);
        }
    }

    // ---- epilogue2: bias+relu -> out (bf16) ----
    {
        int col = w * 16 + l16;
        float bias = B2[col];
#pragma unroll
        for (int r = 0; r < 4; ++r) {
            int m = rowBase + lq * 4 + r;
            float v = fmaxf(acc[r] + bias, 0.0f);
            out[(size_t)m * FEAT + col] = (u16)f2bf(v);
        }
    }
}

// ---------------- pool + head fused: one block per graph ----------------
__global__ __launch_bounds__(128) void pool_head_kernel(
    const u16* __restrict__ h, const int* __restrict__ bnd,
    const float* __restrict__ w1, const float* __restrict__ b1,
    const float* __restrict__ w2, const float* __restrict__ b2,
    float* __restrict__ out)
{
    int g = blockIdx.x;
    int f = threadIdx.x;   // 0..127
    __shared__ float p[FEAT];
    int beg = bnd[g], end = bnd[g + 1];
    float s = 0.0f;
    for (int i = beg; i < end; ++i)
        s += __uint_as_float((u32)h[(size_t)i * FEAT + f] << 16);
    float inv = (end > beg) ? 1.0f / (float)(end - beg) : 1.0f;
    p[f] = s * inv;
    __syncthreads();
    if (f < 64) {
        int j = f;
        float acc = b1[j];
#pragma unroll 8
        for (int k = 0; k < FEAT; ++k) acc = fmaf(p[k], w1[k * 64 + j], acc);
        float hid = fmaxf(acc, 0.0f);
        float prod = hid * w2[j];
#pragma unroll
        for (int off = 32; off > 0; off >>= 1) prod += __shfl_down(prod, off);
        if (j == 0) out[g] = prod + b2[0];
    }
}

extern "C" void kernel_launch(void* const* d_in, const int* in_sizes, int n_in,
                              void* d_out, int out_size, void* d_ws, size_t ws_size,
                              hipStream_t stream) {
    const float* x     = (const float*)d_in[0];
    const int*   ei    = (const int*)d_in[1];
    const int*   batch = (const int*)d_in[2];
    const float* b1[3] = {(const float*)d_in[4], (const float*)d_in[8], (const float*)d_in[12]};
    const float* b2[3] = {(const float*)d_in[6], (const float*)d_in[10], (const float*)d_in[14]};
    const float* hw1 = (const float*)d_in[15];
    const float* hb1 = (const float*)d_in[16];
    const float* hw2 = (const float*)d_in[17];
    const float* hb2 = (const float*)d_in[18];

    int N = in_sizes[0] / FEAT;     // 20000
    int E = in_sizes[1] / 2;        // 640000
    int G = out_size;               // 256

    // workspace layout (16B-aligned chunks)
    u16* wtsH = (u16*)d_ws;                          // 6 * 128*128 bf16
    u16* wtsL = wtsH + (size_t)6 * FEAT * FEAT;      // 6 * 128*128 bf16
    u16* xb  = wtsL + (size_t)6 * FEAT * FEAT;       // N*128 bf16
    u16* hA  = xb + (size_t)N * FEAT;                // N*128 bf16
    u16* hB  = hA + (size_t)N * FEAT;                // N*128 bf16
    u16* esrc = hB + (size_t)N * FEAT;               // N*CAP u16
    int* bnd      = (int*)(esrc + (size_t)N * CAP);  // G+1
    int* cnt      = bnd + (G + 1);                   // N
    int* spillCnt = cnt + N;                         // 1 (+pad)
    int2* spill   = (int2*)(spillCnt + 4);           // SPILLCAP

    const int* src = ei;
    const int* dstv = ei + E;

    int e4Blocks = (E / 4 + 255) / 256;   // 625

    // ---- prep: cvt x (zeros cnt+spillCnt), cvt weights + graph bounds ----
    cvt_x_kernel<<<(N * FEAT / 4 + 255) / 256, 256, 0, stream>>>(
        x, xb, N * FEAT / 4, cnt, N, spillCnt);
    WSet ws;
    ws.w[0] = (const float*)d_in[3];  ws.w[1] = (const float*)d_in[5];
    ws.w[2] = (const float*)d_in[7];  ws.w[3] = (const float*)d_in[9];
    ws.w[4] = (const float*)d_in[11]; ws.w[5] = (const float*)d_in[13];
    cvt_wt_bounds_kernel<<<dim3(64, 7), 256, 0, stream>>>(ws, wtsH, wtsL, batch, bnd, N, G);

    // ---- bucket scatter (replaces hist+scan+csort) ----
    csort_bucket_kernel<<<e4Blocks, 256, 0, stream>>>(
        src, dstv, cnt, esrc, spillCnt, spill, E);

    // ---- 3 fused GIN layers, ping-pong buffers (NO in-place aliasing) ----
    int layerBlocks = (N + 15) / 16;   // 1250
    const u16* lin[3] = {xb, hA, hB};
    u16*       lout[3] = {hA, hB, hA};
    for (int l = 0; l < 3; ++l) {
        gin_layer_kernel<<<layerBlocks, 512, 0, stream>>>(
            lin[l], cnt, esrc, spillCnt, spill,
            wtsH + (size_t)(2 * l) * FEAT * FEAT, wtsL + (size_t)(2 * l) * FEAT * FEAT, b1[l],
            wtsH + (size_t)(2 * l + 1) * FEAT * FEAT, wtsL + (size_t)(2 * l + 1) * FEAT * FEAT, b2[l],
            lout[l], N);
    }

    // ---- pool + head (fused) ----
    pool_head_kernel<<<G, 128, 0, stream>>>(hA, bnd, hw1, hb1, hw2, hb2, (float*)d_out);
}